// Round 7
// baseline (219.121 us; speedup 1.0000x reference)
//
#include <hip/hip_runtime.h>

// ROIAlign3d: x=[2,256,16,64,64] f32, rois=[64,5] -> out=[64,256,16,7,7] f32.
// R8: R7 skeleton + rank-1 separable bilinear. The 2x2-sample 16-tap sum
// factorizes: out = (sum_gy yvec)^T P (sum_gx xvec) -- a 4-row x 4-col patch
// with separable weights (valid mask folds per-axis as 0.5*vy, 0.5*vx).
// y-part depends only on ph, x-part only on pw -> table = 7 y + 7 x entries
// (built by 14 threads). Phase B per output: 4 table reads + 4 read2 tap
// pairs + 20 FMA (was 4 samples x 6 ds-ops). Staging loads issued BEFORE
// table build so global latency hides the build VALU.

#define NBINS 49
#define P     8             // t-planes per block (half of T)
#define MAXB4 85            // max float4 per plane box (17 rows x 5)

__global__ __launch_bounds__(256) void roialign3d_kernel(
    const float* __restrict__ x, const float* __restrict__ rois,
    float* __restrict__ out)
{
    constexpr int C = 256, T = 16, H = 64, W = 64;
    constexpr float SCALE = 0.0625f;
    constexpr int TOT = 2 * C * T * H * W;   // 33,554,432 elements

    __shared__ float4 s_box4[P * MAXB4];     // 10,880 B
    __shared__ int4   s_yro[7];              // row offsets (dwords)
    __shared__ float4 s_ywt[7];              // row weights
    __shared__ int2   s_xco[7];              // col offsets (dwords)
    __shared__ float4 s_xwt[7];              // col weights

    const int b   = blockIdx.x;
    const int c   = b >> 7;          // channel outer
    const int rg  = b & 127;         // roi inner -> cross-roi L2 reuse
    const int r   = rg >> 1;
    const int g   = rg & 1;          // which half of T
    const int tid = threadIdx.x;

    // ---- uniform roi params (scalar loads, r uniform) ----
    const float r1 = rois[r * 5 + 1], r2 = rois[r * 5 + 2];
    const float r3 = rois[r * 5 + 3], r4 = rois[r * 5 + 4];
    const int   bidx = (int)rois[r * 5 + 0];

    const float sw_ = r1 * SCALE, sh_ = r2 * SCALE;
    const float ew_ = r3 * SCALE, eh_ = r4 * SCALE;
    const float bin_w = fmaxf(ew_ - sw_, 1.0f) * (1.0f / 7.0f);
    const float bin_h = fmaxf(eh_ - sh_, 1.0f) * (1.0f / 7.0f);

    // exact sampled extents (monotone; first sample +0.25*bin, last +6.75)
    const float ys_min = sh_ + 0.25f * bin_h, ys_max = sh_ + 6.75f * bin_h;
    const float xs_min = sw_ + 0.25f * bin_w, xs_max = sw_ + 6.75f * bin_w;
    const int y_lo  = (int)floorf(fminf(fmaxf(ys_min, 0.0f), (float)(H - 1)));
    const int y0mx  = (int)floorf(fminf(fmaxf(ys_max, 0.0f), (float)(H - 1)));
    const int x_lo  = (int)floorf(fminf(fmaxf(xs_min, 0.0f), (float)(W - 1)));
    const int x0mx  = (int)floorf(fminf(fmaxf(xs_max, 0.0f), (float)(W - 1)));
    const int x4_lo = x_lo & ~3;

    const int nrows = min(y0mx + 1, H - 1) - y_lo + 1;   // <= 17
    const int ncol4 = ((x0mx + 1 - x4_lo) >> 2) + 1;     // <= 5
    const int rowst = ncol4 << 2;                        // dwords per row
    const int nrc4  = nrows * ncol4;                     // float4 per plane
    const int PS4   = nrc4 | 1;                          // odd plane stride

    // ---- stage exact box for 8 planes FIRST (loads in flight early) ----
    {
        const int total = P * nrc4;                 // <= 680
        const unsigned inv_nrc = 65535u / (unsigned)nrc4  + 1u;  // exact i<680
        const unsigned inv_c   = 65535u / (unsigned)ncol4 + 1u;  // exact rem<85
        const int pbase = ((bidx * C + c) * T + (g << 3)) << 12; // elem (c,t0)
        for (int i = tid; i < total; i += 256) {    // ~2 iters typical
            const int p   = (int)(((unsigned)i * inv_nrc) >> 16);
            const int rem = i - p * nrc4;
            const int row = (int)(((unsigned)rem * inv_c) >> 16);
            const int col = rem - row * ncol4;
            int sidx = pbase + (p << 12) + ((y_lo + row) << 6) + x4_lo + (col << 2);
            sidx = min(sidx, TOT - 4);              // array-end guard
            s_box4[p * PS4 + rem] = *(const float4*)(x + sidx);
        }
    }

    // ---- tiny separable tables: 7 y-entries + 7 x-entries ----
    if (tid < 14) {
        const int k = (tid < 7) ? tid : tid - 7;
        if (tid < 7) {
            int   ro[2][2]; float wy[2][2];
#pragma unroll
            for (int gy = 0; gy < 2; ++gy) {
                const float ys = sh_ + ((float)k + (gy ? 0.75f : 0.25f)) * bin_h;
                const bool  vy = (ys >= -1.0f) && (ys <= (float)H);
                const float yc = fminf(fmaxf(ys, 0.0f), (float)(H - 1));
                const int   y0 = (int)floorf(yc);
                const int   y1 = min(y0 + 1, H - 1);
                const float ly = yc - (float)y0;
                const float m  = vy ? 0.5f : 0.0f;
                ro[gy][0] = (y0 - y_lo) * rowst;
                ro[gy][1] = (y1 - y_lo) * rowst;
                wy[gy][0] = (1.0f - ly) * m;
                wy[gy][1] = ly * m;
            }
            s_yro[k] = make_int4(ro[0][0], ro[0][1], ro[1][0], ro[1][1]);
            s_ywt[k] = make_float4(wy[0][0], wy[0][1], wy[1][0], wy[1][1]);
        } else {
            int   co[2]; float wx[2][2];
#pragma unroll
            for (int gx = 0; gx < 2; ++gx) {
                const float xs = sw_ + ((float)k + (gx ? 0.75f : 0.25f)) * bin_w;
                const bool  vx = (xs >= -1.0f) && (xs <= (float)W);
                const float xc = fminf(fmaxf(xs, 0.0f), (float)(W - 1));
                const int   x0 = (int)floorf(xc);
                const float lx = xc - (float)x0;
                const float hx = 1.0f - lx;
                const bool  xpair = (x0 < W - 1);
                const float m  = vx ? 0.5f : 0.0f;
                co[gx] = x0 - x4_lo;                    // 0..18
                wx[gx][0] = (xpair ? hx : (hx + lx)) * m;
                wx[gx][1] = (xpair ? lx : 0.0f) * m;
            }
            s_xco[k] = make_int2(co[0], co[1]);
            s_xwt[k] = make_float4(wx[0][0], wx[0][1], wx[1][0], wx[1][1]);
        }
    }
    __syncthreads();

    // ---- Phase B: lane = plane (8-lane groups), bin uniform per group ----
    const int l    = tid & 63;
    const int w    = tid >> 6;          // wave 0..3
    const int pl   = l & 7;             // plane 0..7
    const int grp  = l >> 3;            // 0..7
    const int slot = (w << 3) + grp;    // 0..31
    const float* __restrict__ bx = (const float*)s_box4 + pl * (PS4 << 2);
    const int t = (g << 3) + pl;
    float* __restrict__ op = out + (size_t)(((r * C + c) * T + t) * NBINS);

    for (int bin = slot; bin < NBINS; bin += 32) {  // 1..2 bins per lane
        const int ph = (bin * 9363) >> 16;          // bin/7 (exact for <49)
        const int pw = bin - ph * 7;
        const int4   ro = s_yro[ph];
        const float4 wy = s_ywt[ph];
        const int2   cc = s_xco[pw];
        const float4 wx = s_xwt[pw];

        const float* r0 = bx + ro.x;
        const float* r1_ = bx + ro.y;
        const float* r2_ = bx + ro.z;
        const float* r3_ = bx + ro.w;
        float acc;
        {
            const float t0 = wx.x * r0[cc.x] + wx.y * r0[cc.x + 1]
                           + wx.z * r0[cc.y] + wx.w * r0[cc.y + 1];
            acc = wy.x * t0;
        }
        {
            const float t1 = wx.x * r1_[cc.x] + wx.y * r1_[cc.x + 1]
                           + wx.z * r1_[cc.y] + wx.w * r1_[cc.y + 1];
            acc += wy.y * t1;
        }
        {
            const float t2 = wx.x * r2_[cc.x] + wx.y * r2_[cc.x + 1]
                           + wx.z * r2_[cc.y] + wx.w * r2_[cc.y + 1];
            acc += wy.z * t2;
        }
        {
            const float t3 = wx.x * r3_[cc.x] + wx.y * r3_[cc.x + 1]
                           + wx.z * r3_[cc.y] + wx.w * r3_[cc.y + 1];
            acc += wy.w * t3;
        }
        op[bin] = acc;
    }
}

extern "C" void kernel_launch(void* const* d_in, const int* in_sizes, int n_in,
                              void* d_out, int out_size, void* d_ws, size_t ws_size,
                              hipStream_t stream) {
    const float* x    = (const float*)d_in[0];
    const float* rois = (const float*)d_in[1];
    float* out = (float*)d_out;

    // 64 rois * 256 channels * 2 t-halves = 32768 blocks, roi-inner
    roialign3d_kernel<<<dim3(32768), dim3(256), 0, stream>>>(x, rois, out);
}